// Round 2
// baseline (1701.919 us; speedup 1.0000x reference)
//
#include <hip/hip_runtime.h>

typedef __bf16 bf16;
typedef __bf16 bf16x8 __attribute__((ext_vector_type(8)));
typedef float f32x4 __attribute__((ext_vector_type(4)));

#define DI __device__ __forceinline__

constexpr int BS = 4096, DM = 1024, NH = 16;
constexpr long MR = (long)BS * 8;  // 32768 rows

DI void async_cp16(const void* g, void* l) {
  __builtin_amdgcn_global_load_lds(
      (const __attribute__((address_space(1))) void*)g,
      (__attribute__((address_space(3))) void*)l, 16, 0, 0);
}

// ---------------------------------------------------------------------------
// fp32 -> bf16 cast, 8 elems/thread
// ---------------------------------------------------------------------------
__global__ __launch_bounds__(256) void cast_f32_bf16(
    const float* __restrict__ s, bf16* __restrict__ d, int n) {
  const int i = (blockIdx.x * 256 + threadIdx.x) * 8;
  if (i >= n) return;
  float4 a = *(const float4*)(s + i);
  float4 b = *(const float4*)(s + i + 4);
  bf16x8 o;
  o[0] = (bf16)a.x; o[1] = (bf16)a.y; o[2] = (bf16)a.z; o[3] = (bf16)a.w;
  o[4] = (bf16)b.x; o[5] = (bf16)b.y; o[6] = (bf16)b.z; o[7] = (bf16)b.w;
  *(bf16x8*)(d + i) = o;
}

// ---------------------------------------------------------------------------
// C[Mr x N] = A[Mr x K] @ W[N x K]^T (+ addsrc), bf16 in, fp32 accum.
// MODE 0: store bf16, no add. MODE 1: store fp32, add fp32 addsrc.
// MODE 2: store fp32, add bf16 addsrc.
// BM=128, BK=32, 256 threads (4 waves). BN=128: waves 2x2, 4x4 MFMA tiles.
// BN=64: waves 4x1, 2x4 tiles. Staging via global_load_lds width=16.
// ---------------------------------------------------------------------------
template <int BN, int MODE>
__global__ __launch_bounds__(256, 2) void gemm_bt(
    const bf16* __restrict__ A, const bf16* __restrict__ W, void* __restrict__ Cv,
    const void* __restrict__ addv, int N, int K) {
  constexpr int BM = 128, BK = 32;
  constexpr int MI = (BN == 128) ? 4 : 2;
  constexpr int NI = 4;
  __shared__ __align__(16) bf16 sA[BM * BK];
  __shared__ __align__(16) bf16 sB[BN * BK];

  const int tid = threadIdx.x;
  const int wv = tid >> 6;
  const int lane = tid & 63;
  const int bm = blockIdx.x * BM;
  const int bn = blockIdx.y * BN;
  const int wm = (BN == 128) ? (wv >> 1) * 64 : wv * 32;
  const int wn = (BN == 128) ? (wv & 1) * 64 : 0;
  const int q4 = lane >> 4;
  const int r16 = lane & 15;
  const int sr = lane >> 2;
  const int sc = (lane & 3) * 8;

  const f32x4 zero = {0.f, 0.f, 0.f, 0.f};
  f32x4 acc[MI][NI];
#pragma unroll
  for (int i = 0; i < MI; i++)
#pragma unroll
    for (int j = 0; j < NI; j++) acc[i][j] = zero;

  for (int k0 = 0; k0 < K; k0 += BK) {
#pragma unroll
    for (int i = 0; i < 2; i++) {
      const int rg = (wv * 2 + i) * 16;
      async_cp16(A + (size_t)(bm + rg + sr) * K + k0 + sc, &sA[rg * BK]);
    }
    if (BN == 128) {
#pragma unroll
      for (int i = 0; i < 2; i++) {
        const int rg = (wv * 2 + i) * 16;
        async_cp16(W + (size_t)(bn + rg + sr) * K + k0 + sc, &sB[rg * BK]);
      }
    } else {
      const int rg = wv * 16;
      async_cp16(W + (size_t)(bn + rg + sr) * K + k0 + sc, &sB[rg * BK]);
    }
    __syncthreads();
    bf16x8 aF[MI], bF[NI];
#pragma unroll
    for (int i = 0; i < MI; i++)
      aF[i] = *(const bf16x8*)&sA[(wm + i * 16 + r16) * BK + q4 * 8];
#pragma unroll
    for (int j = 0; j < NI; j++)
      bF[j] = *(const bf16x8*)&sB[(wn + j * 16 + r16) * BK + q4 * 8];
#pragma unroll
    for (int i = 0; i < MI; i++)
#pragma unroll
      for (int j = 0; j < NI; j++)
        acc[i][j] = __builtin_amdgcn_mfma_f32_16x16x32_bf16(aF[i], bF[j],
                                                            acc[i][j], 0, 0, 0);
    __syncthreads();
  }

  // C/D layout: col = lane&15, row = quad*4 + reg  [m89/m91 verified]
#pragma unroll
  for (int i = 0; i < MI; i++) {
    const int row = bm + wm + i * 16 + q4 * 4;
#pragma unroll
    for (int j = 0; j < NI; j++) {
      const int col = bn + wn + j * 16 + r16;
#pragma unroll
      for (int r = 0; r < 4; r++) {
        const size_t idx = (size_t)(row + r) * N + col;
        const float vv = acc[i][j][r];
        if (MODE == 0) {
          ((bf16*)Cv)[idx] = (bf16)vv;
        } else if (MODE == 1) {
          ((float*)Cv)[idx] = vv + ((const float*)addv)[idx];
        } else {
          ((float*)Cv)[idx] = vv + (float)((const bf16*)addv)[idx];
        }
      }
    }
  }
}

// ---------------------------------------------------------------------------
// scores[b,h,i,j] = dot64(qh[b,i,h*64:], kh[b,j,h*64:]) / 8 ; global atomic min
// wave per (b,h): lane -> (i=lane>>3, j=lane&7)
// ---------------------------------------------------------------------------
__global__ __launch_bounds__(256) void scores_kernel(
    const bf16* __restrict__ qh, const bf16* __restrict__ kh,
    float* __restrict__ sc, unsigned* __restrict__ minp) {
  __shared__ __align__(16) bf16 sQ[4][8 * 72];
  __shared__ __align__(16) bf16 sK[4][8 * 72];
  const int wv = threadIdx.x >> 6, lane = threadIdx.x & 63;
  const int pair = blockIdx.x * 4 + wv;
  const int b = pair >> 4, h = pair & 15;
  const int i8 = lane >> 3, c8 = lane & 7;
  const size_t g = (size_t)(b * 8 + i8) * DM + h * 64 + c8 * 8;
  *(uint4*)&sQ[wv][i8 * 72 + c8 * 8] = *(const uint4*)&qh[g];
  *(uint4*)&sK[wv][i8 * 72 + c8 * 8] = *(const uint4*)&kh[g];
  __syncthreads();
  const int i = lane >> 3, j = lane & 7;
  float acc = 0.f;
#pragma unroll
  for (int c = 0; c < 8; c++) {
    bf16x8 qv = *(const bf16x8*)&sQ[wv][i * 72 + c * 8];
    bf16x8 kv = *(const bf16x8*)&sK[wv][j * 72 + c * 8];
#pragma unroll
    for (int e = 0; e < 8; e++) acc += (float)qv[e] * (float)kv[e];
  }
  acc *= 0.125f;  // 1/sqrt(D_K)
  sc[(size_t)pair * 64 + lane] = acc;
  float m = acc;
#pragma unroll
  for (int off = 1; off < 64; off <<= 1) m = fminf(m, __shfl_xor(m, off));
  if (lane == 0) {
    unsigned bits = __float_as_uint(m);
    unsigned enc = (bits & 0x80000000u) ? ~bits : (bits | 0x80000000u);
    atomicMin(minp, enc);
  }
}

__global__ void init_min(unsigned* p) { *p = 0xFFFFFFFFu; }

// ---------------------------------------------------------------------------
// per (b,h): s /= |gmin|; per row: s /= max(||s||2,1e-12); softmax; out = P@V
// ---------------------------------------------------------------------------
__global__ __launch_bounds__(256) void attn_av(
    const float* __restrict__ sc, const bf16* __restrict__ vh,
    const unsigned* __restrict__ minp, bf16* __restrict__ outp) {
  __shared__ __align__(16) bf16 sV[4][8 * 64];
  __shared__ float sP[4][64];
  const int wv = threadIdx.x >> 6, lane = threadIdx.x & 63;
  const int pair = blockIdx.x * 4 + wv;
  const int b = pair >> 4, h = pair & 15;
  const int i8 = lane >> 3, c8 = lane & 7;
  *(uint4*)&sV[wv][i8 * 64 + c8 * 8] =
      *(const uint4*)&vh[(size_t)(b * 8 + i8) * DM + h * 64 + c8 * 8];
  const unsigned enc = *minp;
  const unsigned bits = (enc & 0x80000000u) ? (enc & 0x7fffffffu) : ~enc;
  const float scale = 1.0f / fabsf(__uint_as_float(bits));
  float s = sc[(size_t)pair * 64 + lane] * scale;
  float ss = s * s;
  ss += __shfl_xor(ss, 1); ss += __shfl_xor(ss, 2); ss += __shfl_xor(ss, 4);
  s /= fmaxf(sqrtf(ss), 1e-12f);
  float mx = s;
  mx = fmaxf(mx, __shfl_xor(mx, 1));
  mx = fmaxf(mx, __shfl_xor(mx, 2));
  mx = fmaxf(mx, __shfl_xor(mx, 4));
  const float e = expf(s - mx);
  float den = e;
  den += __shfl_xor(den, 1); den += __shfl_xor(den, 2); den += __shfl_xor(den, 4);
  sP[wv][lane] = e / den;
  __syncthreads();
  const int d = lane;
  float o[8] = {0.f, 0.f, 0.f, 0.f, 0.f, 0.f, 0.f, 0.f};
#pragma unroll
  for (int j = 0; j < 8; j++) {
    const float vval = (float)sV[wv][j * 64 + d];
#pragma unroll
    for (int i = 0; i < 8; i++) o[i] += sP[wv][i * 8 + j] * vval;
  }
#pragma unroll
  for (int i = 0; i < 8; i++)
    outp[(size_t)(b * 8 + i) * DM + h * 64 + d] = (bf16)o[i];
}

// ---------------------------------------------------------------------------
// LayerNorm per row of 1024 (biased var, eps=1e-10). fp32 in, bf16 out.
// ---------------------------------------------------------------------------
__global__ __launch_bounds__(256) void ln_kernel(
    const float* __restrict__ y, const float* __restrict__ g,
    const float* __restrict__ bta, bf16* __restrict__ x) {
  const int wv = threadIdx.x >> 6, lane = threadIdx.x & 63;
  const size_t row = (size_t)blockIdx.x * 4 + wv;
  const size_t base = row * DM + lane * 16;
  float vals[16];
#pragma unroll
  for (int c = 0; c < 4; c++) {
    float4 t = *(const float4*)&y[base + c * 4];
    vals[c * 4 + 0] = t.x; vals[c * 4 + 1] = t.y;
    vals[c * 4 + 2] = t.z; vals[c * 4 + 3] = t.w;
  }
  float sum = 0.f, sq = 0.f;
#pragma unroll
  for (int e = 0; e < 16; e++) { sum += vals[e]; sq += vals[e] * vals[e]; }
#pragma unroll
  for (int off = 1; off < 64; off <<= 1) {
    sum += __shfl_xor(sum, off);
    sq += __shfl_xor(sq, off);
  }
  const float mu = sum * (1.f / 1024.f);
  const float var = sq * (1.f / 1024.f) - mu * mu;
  const float rstd = rsqrtf(var + 1e-10f);
  const int col = lane * 16;
  bf16x8 o0, o1;
#pragma unroll
  for (int e = 0; e < 16; e++) {
    const float xv = (vals[e] - mu) * rstd * g[col + e] + bta[col + e];
    if (e < 8) o0[e] = (bf16)xv; else o1[e - 8] = (bf16)xv;
  }
  *(bf16x8*)&x[base] = o0;
  *(bf16x8*)&x[base + 8] = o1;
}

// ---------------------------------------------------------------------------
// ExternalAttention softmax: a = softmax(t, modal axis(8)); a /= sum_S(a)
// wave per batch; lane = s (0..63)
// ---------------------------------------------------------------------------
__global__ __launch_bounds__(256) void ext_softmax(
    const bf16* __restrict__ t, bf16* __restrict__ a) {
  const int wv = threadIdx.x >> 6, lane = threadIdx.x & 63;
  const int b = blockIdx.x * 4 + wv;
  float v[8];
#pragma unroll
  for (int i = 0; i < 8; i++) v[i] = (float)t[(size_t)(b * 8 + i) * 64 + lane];
  float mx = v[0];
#pragma unroll
  for (int i = 1; i < 8; i++) mx = fmaxf(mx, v[i]);
  float e[8], sum = 0.f;
#pragma unroll
  for (int i = 0; i < 8; i++) { e[i] = expf(v[i] - mx); sum += e[i]; }
  const float inv = 1.f / sum;
#pragma unroll
  for (int i = 0; i < 8; i++) {
    float r = e[i] * inv;
    float rs = r;
#pragma unroll
    for (int off = 1; off < 64; off <<= 1) rs += __shfl_xor(rs, off);
    a[(size_t)(b * 8 + i) * 64 + lane] = (bf16)(r / rs);
  }
}

// ---------------------------------------------------------------------------
extern "C" void kernel_launch(void* const* d_in, const int* in_sizes, int n_in,
                              void* d_out, int out_size, void* d_ws,
                              size_t ws_size, hipStream_t stream) {
  (void)in_sizes; (void)n_in; (void)out_size; (void)ws_size;
  const float* q = (const float*)d_in[0];
  const float* k = (const float*)d_in[1];
  const float* v = (const float*)d_in[2];
  const float* Wq = (const float*)d_in[3];
  const float* Wk = (const float*)d_in[4];
  const float* Wv = (const float*)d_in[5];
  const float* Wfc = (const float*)d_in[6];
  const float* gamma = (const float*)d_in[7];
  const float* beta = (const float*)d_in[8];
  const float* Wmk = (const float*)d_in[9];
  const float* Wmv = (const float*)d_in[10];

  // d_out (128 MB fp32) doubles as two 64 MB bf16 scratch slots early on.
  bf16* D1 = (bf16*)d_out;
  bf16* D2 = (bf16*)d_out + (size_t)MR * DM;

  char* w = (char*)d_ws;
  unsigned* minp = (unsigned*)w;
  bf16* Wqb = (bf16*)(w + 4096);
  bf16* Wkb = (bf16*)(w + 4096 + (1u << 21));
  bf16* Wvb = (bf16*)(w + 4096 + (2u << 21));
  bf16* Wfcb = (bf16*)(w + 4096 + (3u << 21));
  bf16* Wmkb = (bf16*)(w + 4096 + (4u << 21));
  bf16* Wmvb = (bf16*)(w + 4096 + (4u << 21) + 131072);
  float* scores = (float*)(w + (16u << 20));   // 16 MB fp32
  bf16* tb = (bf16*)(w + (32u << 20));         // 4 MB
  bf16* ab = (bf16*)(w + (36u << 20));         // 4 MB
  bf16* W1 = (bf16*)(w + (40u << 20));         // 64 MB row slot

  const dim3 blk(256);
  const dim3 gBig(MR / 128, DM / 128);
  const int NROW = (int)(MR * DM);  // 33554432

  auto cast = [&](const float* s, bf16* d, int n) {
    cast_f32_bf16<<<dim3(n / 2048), blk, 0, stream>>>(s, d, n);
  };

  init_min<<<dim3(1), dim3(1), 0, stream>>>(minp);
  cast(Wq, Wqb, DM * DM); cast(Wk, Wkb, DM * DM);
  cast(Wv, Wvb, DM * DM); cast(Wfc, Wfcb, DM * DM);
  cast(Wmk, Wmkb, 64 * DM); cast(Wmv, Wmvb, DM * 64);

  cast(q, D1, NROW);
  gemm_bt<128, 0><<<gBig, blk, 0, stream>>>(D1, Wqb, W1, nullptr, DM, DM);   // qh->W1
  cast(k, D2, NROW);
  gemm_bt<128, 0><<<gBig, blk, 0, stream>>>(D2, Wkb, D1, nullptr, DM, DM);   // kh->D1
  scores_kernel<<<dim3(BS * NH / 4), blk, 0, stream>>>(W1, D1, scores, minp);
  cast(v, D2, NROW);
  gemm_bt<128, 0><<<gBig, blk, 0, stream>>>(D2, Wvb, D1, nullptr, DM, DM);   // vh->D1
  attn_av<<<dim3(BS * NH / 4), blk, 0, stream>>>(scores, D1, minp, W1);      // attn->W1
  gemm_bt<128, 1><<<gBig, blk, 0, stream>>>(W1, Wfcb, d_out, q, DM, DM);     // y fp32 -> d_out
  ln_kernel<<<dim3(MR / 4), blk, 0, stream>>>((const float*)d_out, gamma, beta, W1);  // x->W1
  gemm_bt<64, 0><<<dim3(MR / 128, 1), blk, 0, stream>>>(W1, Wmkb, tb, nullptr, 64, DM);
  ext_softmax<<<dim3(BS / 4), blk, 0, stream>>>(tb, ab);
  gemm_bt<128, 2><<<gBig, blk, 0, stream>>>(ab, Wmvb, d_out, W1, DM, 64);    // out = q1 + x
}

// Round 3
// 987.644 us; speedup vs baseline: 1.7232x; 1.7232x over previous
//
#include <hip/hip_runtime.h>

typedef __bf16 bf16;
typedef __bf16 bf16x8 __attribute__((ext_vector_type(8)));
typedef float f32x4 __attribute__((ext_vector_type(4)));

#define DI __device__ __forceinline__

constexpr int BS = 4096, DM = 1024, NH = 16;
constexpr long MR = (long)BS * 8;  // 32768 rows

DI void async_cp16(const void* g, void* l) {
  __builtin_amdgcn_global_load_lds(
      (const __attribute__((address_space(1))) void*)g,
      (__attribute__((address_space(3))) void*)l, 16, 0, 0);
}

// ---------------------------------------------------------------------------
// fp32 -> bf16 cast, 8 elems/thread
// ---------------------------------------------------------------------------
__global__ __launch_bounds__(256) void cast_f32_bf16(
    const float* __restrict__ s, bf16* __restrict__ d, int n) {
  const int i = (blockIdx.x * 256 + threadIdx.x) * 8;
  if (i >= n) return;
  float4 a = *(const float4*)(s + i);
  float4 b = *(const float4*)(s + i + 4);
  bf16x8 o;
  o[0] = (bf16)a.x; o[1] = (bf16)a.y; o[2] = (bf16)a.z; o[3] = (bf16)a.w;
  o[4] = (bf16)b.x; o[5] = (bf16)b.y; o[6] = (bf16)b.z; o[7] = (bf16)b.w;
  *(bf16x8*)(d + i) = o;
}

// ---------------------------------------------------------------------------
// C[Mr x N] = A[Mr x K] @ W[N x K]^T (+ addsrc), bf16 in, fp32 accum.
// MODE 0: store bf16, no add. MODE 1: store fp32, add fp32 addsrc.
// MODE 2: store fp32, add bf16 addsrc.
// ---------------------------------------------------------------------------
template <int BN, int MODE>
__global__ __launch_bounds__(256, 2) void gemm_bt(
    const bf16* __restrict__ A, const bf16* __restrict__ W, void* __restrict__ Cv,
    const void* __restrict__ addv, int N, int K) {
  constexpr int BM = 128, BK = 32;
  constexpr int MI = (BN == 128) ? 4 : 2;
  constexpr int NI = 4;
  __shared__ __align__(16) bf16 sA[BM * BK];
  __shared__ __align__(16) bf16 sB[BN * BK];

  const int tid = threadIdx.x;
  const int wv = tid >> 6;
  const int lane = tid & 63;
  const int bm = blockIdx.x * BM;
  const int bn = blockIdx.y * BN;
  const int wm = (BN == 128) ? (wv >> 1) * 64 : wv * 32;
  const int wn = (BN == 128) ? (wv & 1) * 64 : 0;
  const int q4 = lane >> 4;
  const int r16 = lane & 15;
  const int sr = lane >> 2;
  const int sc = (lane & 3) * 8;

  const f32x4 zero = {0.f, 0.f, 0.f, 0.f};
  f32x4 acc[MI][NI];
#pragma unroll
  for (int i = 0; i < MI; i++)
#pragma unroll
    for (int j = 0; j < NI; j++) acc[i][j] = zero;

  for (int k0 = 0; k0 < K; k0 += BK) {
#pragma unroll
    for (int i = 0; i < 2; i++) {
      const int rg = (wv * 2 + i) * 16;
      async_cp16(A + (size_t)(bm + rg + sr) * K + k0 + sc, &sA[rg * BK]);
    }
    if (BN == 128) {
#pragma unroll
      for (int i = 0; i < 2; i++) {
        const int rg = (wv * 2 + i) * 16;
        async_cp16(W + (size_t)(bn + rg + sr) * K + k0 + sc, &sB[rg * BK]);
      }
    } else {
      const int rg = wv * 16;
      async_cp16(W + (size_t)(bn + rg + sr) * K + k0 + sc, &sB[rg * BK]);
    }
    __syncthreads();
    bf16x8 aF[MI], bF[NI];
#pragma unroll
    for (int i = 0; i < MI; i++)
      aF[i] = *(const bf16x8*)&sA[(wm + i * 16 + r16) * BK + q4 * 8];
#pragma unroll
    for (int j = 0; j < NI; j++)
      bF[j] = *(const bf16x8*)&sB[(wn + j * 16 + r16) * BK + q4 * 8];
#pragma unroll
    for (int i = 0; i < MI; i++)
#pragma unroll
      for (int j = 0; j < NI; j++)
        acc[i][j] = __builtin_amdgcn_mfma_f32_16x16x32_bf16(aF[i], bF[j],
                                                            acc[i][j], 0, 0, 0);
    __syncthreads();
  }

  // C/D layout: col = lane&15, row = quad*4 + reg  [m89/m91 verified]
#pragma unroll
  for (int i = 0; i < MI; i++) {
    const int row = bm + wm + i * 16 + q4 * 4;
#pragma unroll
    for (int j = 0; j < NI; j++) {
      const int col = bn + wn + j * 16 + r16;
#pragma unroll
      for (int r = 0; r < 4; r++) {
        const size_t idx = (size_t)(row + r) * N + col;
        const float vv = acc[i][j][r];
        if (MODE == 0) {
          ((bf16*)Cv)[idx] = (bf16)vv;
        } else if (MODE == 1) {
          ((float*)Cv)[idx] = vv + ((const float*)addv)[idx];
        } else {
          ((float*)Cv)[idx] = vv + (float)((const bf16*)addv)[idx];
        }
      }
    }
  }
}

// ---------------------------------------------------------------------------
// scores[b,h,i,j] = dot64(qh, kh)/8 ; per-block min -> minBlk (NO atomics)
// wave per (b,h): lane -> (i=lane>>3, j=lane&7)
// ---------------------------------------------------------------------------
__global__ __launch_bounds__(256) void scores_kernel(
    const bf16* __restrict__ qh, const bf16* __restrict__ kh,
    float* __restrict__ sc, float* __restrict__ minBlk) {
  __shared__ __align__(16) bf16 sQ[4][8 * 72];
  __shared__ __align__(16) bf16 sK[4][8 * 72];
  __shared__ float sMin[4];
  const int wv = threadIdx.x >> 6, lane = threadIdx.x & 63;
  const int pair = blockIdx.x * 4 + wv;
  const int b = pair >> 4, h = pair & 15;
  const int i8 = lane >> 3, c8 = lane & 7;
  const size_t g = (size_t)(b * 8 + i8) * DM + h * 64 + c8 * 8;
  *(uint4*)&sQ[wv][i8 * 72 + c8 * 8] = *(const uint4*)&qh[g];
  *(uint4*)&sK[wv][i8 * 72 + c8 * 8] = *(const uint4*)&kh[g];
  __syncthreads();
  const int i = lane >> 3, j = lane & 7;
  float acc = 0.f;
#pragma unroll
  for (int c = 0; c < 8; c++) {
    bf16x8 qv = *(const bf16x8*)&sQ[wv][i * 72 + c * 8];
    bf16x8 kv = *(const bf16x8*)&sK[wv][j * 72 + c * 8];
#pragma unroll
    for (int e = 0; e < 8; e++) acc += (float)qv[e] * (float)kv[e];
  }
  acc *= 0.125f;  // 1/sqrt(D_K)
  sc[(size_t)pair * 64 + lane] = acc;
  float m = acc;
#pragma unroll
  for (int off = 1; off < 64; off <<= 1) m = fminf(m, __shfl_xor(m, off));
  if (lane == 0) sMin[wv] = m;
  __syncthreads();
  if (threadIdx.x == 0)
    minBlk[blockIdx.x] =
        fminf(fminf(sMin[0], sMin[1]), fminf(sMin[2], sMin[3]));
}

// single block: fold nb block-minima -> scale = 1/|globalmin|
__global__ __launch_bounds__(256) void reduce_min(
    const float* __restrict__ mb, int nb, float* __restrict__ scalep) {
  float m = 3.4e38f;
  for (int i = threadIdx.x; i < nb; i += 256) m = fminf(m, mb[i]);
#pragma unroll
  for (int off = 1; off < 64; off <<= 1) m = fminf(m, __shfl_xor(m, off));
  __shared__ float sm[4];
  if ((threadIdx.x & 63) == 0) sm[threadIdx.x >> 6] = m;
  __syncthreads();
  if (threadIdx.x == 0) {
    float mm = fminf(fminf(sm[0], sm[1]), fminf(sm[2], sm[3]));
    *scalep = 1.0f / fabsf(mm);
  }
}

// ---------------------------------------------------------------------------
// per (b,h): s *= scale; per row: s /= max(||s||2,1e-12); softmax; out = P@V
// ---------------------------------------------------------------------------
__global__ __launch_bounds__(256) void attn_av(
    const float* __restrict__ sc, const bf16* __restrict__ vh,
    const float* __restrict__ scalep, bf16* __restrict__ outp) {
  __shared__ __align__(16) bf16 sV[4][8 * 64];
  __shared__ float sP[4][64];
  const int wv = threadIdx.x >> 6, lane = threadIdx.x & 63;
  const int pair = blockIdx.x * 4 + wv;
  const int b = pair >> 4, h = pair & 15;
  const int i8 = lane >> 3, c8 = lane & 7;
  *(uint4*)&sV[wv][i8 * 64 + c8 * 8] =
      *(const uint4*)&vh[(size_t)(b * 8 + i8) * DM + h * 64 + c8 * 8];
  const float scale = *scalep;
  float s = sc[(size_t)pair * 64 + lane] * scale;
  float ss = s * s;
  ss += __shfl_xor(ss, 1); ss += __shfl_xor(ss, 2); ss += __shfl_xor(ss, 4);
  s /= fmaxf(sqrtf(ss), 1e-12f);
  float mx = s;
  mx = fmaxf(mx, __shfl_xor(mx, 1));
  mx = fmaxf(mx, __shfl_xor(mx, 2));
  mx = fmaxf(mx, __shfl_xor(mx, 4));
  const float e = expf(s - mx);
  float den = e;
  den += __shfl_xor(den, 1); den += __shfl_xor(den, 2); den += __shfl_xor(den, 4);
  sP[wv][lane] = e / den;
  __syncthreads();
  const int d = lane;
  float o[8] = {0.f, 0.f, 0.f, 0.f, 0.f, 0.f, 0.f, 0.f};
#pragma unroll
  for (int j = 0; j < 8; j++) {
    const float vval = (float)sV[wv][j * 64 + d];
#pragma unroll
    for (int i = 0; i < 8; i++) o[i] += sP[wv][i * 8 + j] * vval;
  }
#pragma unroll
  for (int i = 0; i < 8; i++)
    outp[(size_t)(b * 8 + i) * DM + h * 64 + d] = (bf16)o[i];
}

// ---------------------------------------------------------------------------
// LayerNorm per row of 1024 (biased var, eps=1e-10). fp32 in, bf16 out.
// ---------------------------------------------------------------------------
__global__ __launch_bounds__(256) void ln_kernel(
    const float* __restrict__ y, const float* __restrict__ g,
    const float* __restrict__ bta, bf16* __restrict__ x) {
  const int wv = threadIdx.x >> 6, lane = threadIdx.x & 63;
  const size_t row = (size_t)blockIdx.x * 4 + wv;
  const size_t base = row * DM + lane * 16;
  float vals[16];
#pragma unroll
  for (int c = 0; c < 4; c++) {
    float4 t = *(const float4*)&y[base + c * 4];
    vals[c * 4 + 0] = t.x; vals[c * 4 + 1] = t.y;
    vals[c * 4 + 2] = t.z; vals[c * 4 + 3] = t.w;
  }
  float sum = 0.f, sq = 0.f;
#pragma unroll
  for (int e = 0; e < 16; e++) { sum += vals[e]; sq += vals[e] * vals[e]; }
#pragma unroll
  for (int off = 1; off < 64; off <<= 1) {
    sum += __shfl_xor(sum, off);
    sq += __shfl_xor(sq, off);
  }
  const float mu = sum * (1.f / 1024.f);
  const float var = sq * (1.f / 1024.f) - mu * mu;
  const float rstd = rsqrtf(var + 1e-10f);
  const int col = lane * 16;
  bf16x8 o0, o1;
#pragma unroll
  for (int e = 0; e < 16; e++) {
    const float xv = (vals[e] - mu) * rstd * g[col + e] + bta[col + e];
    if (e < 8) o0[e] = (bf16)xv; else o1[e - 8] = (bf16)xv;
  }
  *(bf16x8*)&x[base] = o0;
  *(bf16x8*)&x[base + 8] = o1;
}

// ---------------------------------------------------------------------------
// ExternalAttention softmax: a = softmax(t, modal axis(8)); a /= sum_S(a)
// ---------------------------------------------------------------------------
__global__ __launch_bounds__(256) void ext_softmax(
    const bf16* __restrict__ t, bf16* __restrict__ a) {
  const int wv = threadIdx.x >> 6, lane = threadIdx.x & 63;
  const int b = blockIdx.x * 4 + wv;
  float v[8];
#pragma unroll
  for (int i = 0; i < 8; i++) v[i] = (float)t[(size_t)(b * 8 + i) * 64 + lane];
  float mx = v[0];
#pragma unroll
  for (int i = 1; i < 8; i++) mx = fmaxf(mx, v[i]);
  float e[8], sum = 0.f;
#pragma unroll
  for (int i = 0; i < 8; i++) { e[i] = expf(v[i] - mx); sum += e[i]; }
  const float inv = 1.f / sum;
#pragma unroll
  for (int i = 0; i < 8; i++) {
    float r = e[i] * inv;
    float rs = r;
#pragma unroll
    for (int off = 1; off < 64; off <<= 1) rs += __shfl_xor(rs, off);
    a[(size_t)(b * 8 + i) * 64 + lane] = (bf16)(r / rs);
  }
}

// ---------------------------------------------------------------------------
extern "C" void kernel_launch(void* const* d_in, const int* in_sizes, int n_in,
                              void* d_out, int out_size, void* d_ws,
                              size_t ws_size, hipStream_t stream) {
  (void)in_sizes; (void)n_in; (void)out_size; (void)ws_size;
  const float* q = (const float*)d_in[0];
  const float* k = (const float*)d_in[1];
  const float* v = (const float*)d_in[2];
  const float* Wq = (const float*)d_in[3];
  const float* Wk = (const float*)d_in[4];
  const float* Wv = (const float*)d_in[5];
  const float* Wfc = (const float*)d_in[6];
  const float* gamma = (const float*)d_in[7];
  const float* beta = (const float*)d_in[8];
  const float* Wmk = (const float*)d_in[9];
  const float* Wmv = (const float*)d_in[10];

  // d_out (128 MB fp32) doubles as two 64 MB bf16 scratch slots early on.
  bf16* D1 = (bf16*)d_out;
  bf16* D2 = (bf16*)d_out + (size_t)MR * DM;

  char* w = (char*)d_ws;
  float* scalep = (float*)w;                          // 4 B
  float* minBlk = (float*)(w + 256);                  // 64 KB
  bf16* Wqb = (bf16*)(w + (1u << 17));
  bf16* Wkb = (bf16*)(w + (1u << 17) + (1u << 21));
  bf16* Wvb = (bf16*)(w + (1u << 17) + (2u << 21));
  bf16* Wfcb = (bf16*)(w + (1u << 17) + (3u << 21));
  bf16* Wmkb = (bf16*)(w + (1u << 17) + (4u << 21));
  bf16* Wmvb = (bf16*)(w + (1u << 17) + (4u << 21) + 131072);
  float* scores = (float*)(w + (16u << 20));   // 16 MB fp32
  bf16* tb = (bf16*)(w + (32u << 20));         // 4 MB
  bf16* ab = (bf16*)(w + (36u << 20));         // 4 MB
  bf16* W1 = (bf16*)(w + (40u << 20));         // 64 MB row slot

  const dim3 blk(256);
  const dim3 gBig(MR / 128, DM / 128);
  const int NROW = (int)(MR * DM);  // 33554432
  const int NBLK = BS * NH / 4;     // 16384

  auto cast = [&](const float* s, bf16* d, int n) {
    cast_f32_bf16<<<dim3(n / 2048), blk, 0, stream>>>(s, d, n);
  };

  cast(Wq, Wqb, DM * DM); cast(Wk, Wkb, DM * DM);
  cast(Wv, Wvb, DM * DM); cast(Wfc, Wfcb, DM * DM);
  cast(Wmk, Wmkb, 64 * DM); cast(Wmv, Wmvb, DM * 64);

  cast(q, D1, NROW);
  gemm_bt<128, 0><<<gBig, blk, 0, stream>>>(D1, Wqb, W1, nullptr, DM, DM);   // qh->W1
  cast(k, D2, NROW);
  gemm_bt<128, 0><<<gBig, blk, 0, stream>>>(D2, Wkb, D1, nullptr, DM, DM);   // kh->D1
  scores_kernel<<<dim3(NBLK), blk, 0, stream>>>(W1, D1, scores, minBlk);
  reduce_min<<<dim3(1), blk, 0, stream>>>(minBlk, NBLK, scalep);
  cast(v, D2, NROW);
  gemm_bt<128, 0><<<gBig, blk, 0, stream>>>(D2, Wvb, D1, nullptr, DM, DM);   // vh->D1
  attn_av<<<dim3(NBLK), blk, 0, stream>>>(scores, D1, scalep, W1);           // attn->W1
  gemm_bt<128, 1><<<gBig, blk, 0, stream>>>(W1, Wfcb, d_out, q, DM, DM);     // y fp32 -> d_out
  ln_kernel<<<dim3(MR / 4), blk, 0, stream>>>((const float*)d_out, gamma, beta, W1);  // x->W1
  gemm_bt<64, 0><<<dim3(MR / 128, 1), blk, 0, stream>>>(W1, Wmkb, tb, nullptr, 64, DM);
  ext_softmax<<<dim3(BS / 4), blk, 0, stream>>>(tb, ab);
  gemm_bt<128, 2><<<gBig, blk, 0, stream>>>(ab, Wmvb, d_out, W1, DM, 64);    // out = q1 + x
}